// Round 4
// baseline (1712.319 us; speedup 1.0000x reference)
//
#include <hip/hip_runtime.h>

#define LOG2E 1.44269504088896340736f

typedef float f32x16 __attribute__((ext_vector_type(16)));
typedef float f32x8  __attribute__((ext_vector_type(8)));

__device__ __forceinline__ float fexp2(float x) { return __builtin_amdgcn_exp2f(x); }
__device__ __forceinline__ float frcp(float x)  { return __builtin_amdgcn_rcpf(x); }

__device__ __forceinline__ float sigmoid_f(float x) {
    return frcp(1.0f + fexp2(-x * LOG2E));
}
__device__ __forceinline__ float tanh_f(float x) {
    float t = fexp2(x * (2.0f * LOG2E));
    return (t - 1.0f) * frcp(t + 1.0f);
}

// Frontend-constant-index loop: indices are constexpr BEFORE any LLVM pass,
// so vector element accesses are insert/extractelement on SSA values — no
// allocas, no scratch, nothing for promote-alloca to salvage.
template <int I> struct IntC { static constexpr int value = I; };
template <int I, int N, typename F>
__device__ __forceinline__ void sfor(F&& f) {
    if constexpr (I < N) { f(IntC<I>{}); sfor<I + 1, N>(f); }
}

// One LSTM cell step over vectors. XIN: f32x8 or f32x16.
template <int DIN, typename XVec>
__device__ __forceinline__ void lstm_cell_v(const float* __restrict__ Wih,   // 64 x DIN
                                            const float* __restrict__ Whh,   // 64 x 16
                                            const float* __restrict__ bih,   // 64
                                            const float* __restrict__ bhh,   // 64
                                            const XVec& x,
                                            const f32x16& hin,
                                            f32x16& c,
                                            f32x16& hout) {
    sfor<0, 16>([&](auto J) {
        constexpr int j = J.value;
        float gi = bih[j]      + bhh[j];
        float gf = bih[16 + j] + bhh[16 + j];
        float gg = bih[32 + j] + bhh[32 + j];
        float go = bih[48 + j] + bhh[48 + j];
        sfor<0, DIN>([&](auto K) {
            constexpr int k = K.value;
            gi += Wih[j * DIN + k]        * x[k];
            gf += Wih[(16 + j) * DIN + k] * x[k];
            gg += Wih[(32 + j) * DIN + k] * x[k];
            go += Wih[(48 + j) * DIN + k] * x[k];
        });
        sfor<0, 16>([&](auto K) {
            constexpr int k = K.value;
            gi += Whh[j * 16 + k]        * hin[k];
            gf += Whh[(16 + j) * 16 + k] * hin[k];
            gg += Whh[(32 + j) * 16 + k] * hin[k];
            go += Whh[(48 + j) * 16 + k] * hin[k];
        });
        float i_ = sigmoid_f(gi);
        float f_ = sigmoid_f(gf);
        float g_ = tanh_f(gg);
        float o_ = sigmoid_f(go);
        float cn = f_ * c[j] + i_ * g_;
        c[j]    = cn;
        hout[j] = o_ * tanh_f(cn);
    });
}

// waves_per_eu(4): VGPR cap 128, occupancy target exactly 4 waves/EU.
// Live state ~110 VGPRs (h0,c0,h1,c1 = 64 + x_t 8 + gate/trans temps).
__global__
__attribute__((amdgpu_flat_work_group_size(256, 256)))
__attribute__((amdgpu_waves_per_eu(4)))
void lstm_fused_kernel(const float* __restrict__ in,     // B x 8 x 8
                       const float* __restrict__ Wih0,   // 64 x 8
                       const float* __restrict__ Whh0,   // 64 x 16
                       const float* __restrict__ bih0,
                       const float* __restrict__ bhh0,
                       const float* __restrict__ Wih1,   // 64 x 16
                       const float* __restrict__ Whh1,   // 64 x 16
                       const float* __restrict__ bih1,
                       const float* __restrict__ bhh1,
                       const float* __restrict__ Wfc,    // 10 x 16
                       const float* __restrict__ bfc,    // 10
                       float* __restrict__ out,          // B x 10
                       int B) {
    int b = blockIdx.x * blockDim.x + threadIdx.x;
    if (b >= B) return;

    const float* xin = in + (size_t)b * 64;

    f32x16 h0 = {}, c0 = {}, h1 = {}, c1 = {};

    sfor<0, 8>([&](auto T) {
        constexpr int t = T.value;
        // 32B contiguous, 32B-aligned vector load (2x global_load_dwordx4,
        // constant offset folds into the instruction immediate).
        f32x8 xt = *(const f32x8*)(xin + t * 8);

        f32x16 nh0 = {};
        lstm_cell_v<8>(Wih0, Whh0, bih0, bhh0, xt, h0, c0, nh0);
        h0 = nh0;

        f32x16 nh1 = {};
        lstm_cell_v<16>(Wih1, Whh1, bih1, bhh1, h0, h1, c1, nh1);
        h1 = nh1;
    });

    // FC on last h1
    float* op = out + (size_t)b * 10;
    sfor<0, 10>([&](auto CI) {
        constexpr int ci = CI.value;
        float acc = bfc[ci];
        sfor<0, 16>([&](auto K) {
            constexpr int k = K.value;
            acc += Wfc[ci * 16 + k] * h1[k];
        });
        op[ci] = acc;
    });
}

extern "C" void kernel_launch(void* const* d_in, const int* in_sizes, int n_in,
                              void* d_out, int out_size, void* d_ws, size_t ws_size,
                              hipStream_t stream) {
    const float* in   = (const float*)d_in[0];
    const float* Wih0 = (const float*)d_in[1];
    const float* Whh0 = (const float*)d_in[2];
    const float* bih0 = (const float*)d_in[3];
    const float* bhh0 = (const float*)d_in[4];
    const float* Wih1 = (const float*)d_in[5];
    const float* Whh1 = (const float*)d_in[6];
    const float* bih1 = (const float*)d_in[7];
    const float* bhh1 = (const float*)d_in[8];
    const float* Wfc  = (const float*)d_in[9];
    const float* bfc  = (const float*)d_in[10];
    float* out = (float*)d_out;

    int B = in_sizes[0] / 64;   // 262144
    int block = 256;
    int grid = (B + block - 1) / block;
    lstm_fused_kernel<<<grid, block, 0, stream>>>(in, Wih0, Whh0, bih0, bhh0,
                                                  Wih1, Whh1, bih1, bhh1,
                                                  Wfc, bfc, out, B);
}